// Round 9
// baseline (707.021 us; speedup 1.0000x reference)
//
#include <hip/hip_runtime.h>
#include <hip/hip_bf16.h>

#define NXD 512
#define NYD 512
#define TD 5
#define BD 4
#define HIDD 64
#define PLANE (NXD*NYD)      /* 262144 */
#define VOL (TD*PLANE)       /* 1310720 */
#define NPB 512              /* phi/cost blocks per batch (16x32 tiles) */

typedef __bf16 bf16x8 __attribute__((ext_vector_type(8)));
typedef __bf16 bf16x4 __attribute__((ext_vector_type(4)));
typedef float  f32x4  __attribute__((ext_vector_type(4)));

// LDS strides: sx 16 B/pixel; sh 80 B/pixel (group stride 5, coprime with 8).
#define SX_PS 16
#define SXW 36               /* sx cols: 32 output + 2+2 halo */
#define SH_PS 80

// W1r: [kt=3][ch=64][32 bf16]   k = tap*8 + c8   (taps 9..11 zero-padded)
// W2r: [h=2][tap=9][out=16][32] k(within half) = c32; out 5..15 zero
#define W1R_ELEMS (3*64*32)   /* 6144 */
#define W2R_ELEMS (2*9*16*32) /* 9216 */

__global__ __launch_bounds__(256)
void prep_weights(const float* __restrict__ W1, const float* __restrict__ W2,
                  __bf16* __restrict__ W1r, __bf16* __restrict__ W2r)
{
    int id = blockIdx.x * 256 + threadIdx.x;
    if (id < W1R_ELEMS) {
        int kt  = id >> 11;
        int rem = id & 2047;
        int n   = rem >> 5;
        int kk  = rem & 31;
        int k   = kt * 32 + kk;
        int tap = k >> 3, c = k & 7;
        float v = 0.f;
        if (tap <= 8 && c < 5)
            v = W1[(n * 5 + c) * 9 + tap];      // W1 [64][5][3][3]
        W1r[id] = (__bf16)v;
    } else if (id < W1R_ELEMS + W2R_ELEMS) {
        int id2 = id - W1R_ELEMS;
        int h    = id2 / 4608;
        int rem  = id2 - h * 4608;
        int tap  = rem >> 9;
        int rem2 = rem & 511;
        int n    = rem2 >> 5;
        int c    = rem2 & 31;
        float v = 0.f;
        if (n < 5)
            v = W2[(n * HIDD + h * 32 + c) * 9 + tap];  // W2 [5][64][3][3]
        W2r[id2] = (__bf16)v;
    }
}

// ---------------------------------------------------------------------------
// Fused phi (+ optional cost of its INPUT).  r8 structure (543us) widened to
// TWO output tiles per block (16x32, gy direction):
//  * ONE staged tile 20x36 (720 px, contiguous 36-col rows) amortizes the
//    stage-latency exposure and halo over 2 tiles (720 vs 2x400 px).
//  * ONE cost section covers both tiles (one shuffle-reduce chain).
//  * conv pipeline = r8 body verbatim inside a ct-loop (sx col base +ct*16);
//    sh layout / conv2 / epilogue untouched; acc2 reset per ct; tile-0
//    epilogue stores overlap tile-1 conv.
//  * 2048 blocks (was 4096): half the ramp/tail rounds per dispatch.
// LDS = 720*16 + 324*80 = 37,440 -> 4 blocks/CU (16 waves/CU, >= achieved).
// ---------------------------------------------------------------------------
template<int INP, int OUTP>
__global__ __launch_bounds__(256, 4)
void phi_mfma(const float* __restrict__ xin,
              const __bf16* __restrict__ xin_pk,
              const __bf16* __restrict__ W1r, const __bf16* __restrict__ W2r,
              const float* __restrict__ b1, const float* __restrict__ b2,
              const float* __restrict__ gt, const float* __restrict__ yobs,
              const int* __restrict__ mask,
              float* __restrict__ xout, __bf16* __restrict__ xout_pk,
              float* __restrict__ cpart, int blend)
{
    __shared__ __align__(16) char sx[720 * SX_PS];  // 11520 B (20x36 tile)
    __shared__ __align__(16) char sh[324 * SH_PS];  // 25920 B

    const int tid   = threadIdx.x;
    const int wv    = tid >> 6;
    const int lane  = tid & 63;
    const int l15   = lane & 15;
    const int quad  = lane >> 4;
    const int b     = blockIdx.z;
    const int gx0   = blockIdx.x * 16;
    const int gy0   = blockIdx.y * 32;

    // ---- stage x tile 20x36 (halo 2): one b128 write per pixel ----
    for (int p = tid; p < 720; p += 256) {
        const int u  = p / SXW;
        const int v  = p - u * SXW;
        const int gx = gx0 + u - 2;
        const int gy = gy0 + v - 2;
        bf16x8 pix = {(__bf16)0.f,(__bf16)0.f,(__bf16)0.f,(__bf16)0.f,
                      (__bf16)0.f,(__bf16)0.f,(__bf16)0.f,(__bf16)0.f};
        if (gx >= 0 && gx < NXD && gy >= 0 && gy < NYD) {
            if constexpr (INP == 0) {
                const float* src = xin + (size_t)b * VOL + (size_t)gx * NYD + gy;
                #pragma unroll
                for (int c = 0; c < TD; ++c) pix[c] = (__bf16)src[(size_t)c * PLANE];
            } else {
                pix = *(const bf16x8*)(xin_pk +
                        ((size_t)b * PLANE + (size_t)gx * NYD + gy) * 8);
            }
        }
        *(bf16x8*)(sx + p * SX_PS) = pix;
    }
    __syncthreads();

    // ---- fused cost of the INPUT x (rows 0..3), both tiles ----
    if (cpart) {
        const int ti = tid >> 4, tj = tid & 15;
        float mse = 0.f, dy = 0.f, q = 0.f;
        for (int ct = 0; ct < 2; ++ct) {
            const int col = ct * 16 + tj;
            const int u   = ti + 2, v = col + 2;
            const size_t gbase = (size_t)b * VOL + (size_t)(gx0 + ti) * NYD + (gy0 + col);
            float xv[TD];
            if constexpr (INP == 0) {
                #pragma unroll
                for (int c = 0; c < TD; ++c) xv[c] = xin[gbase + (size_t)c * PLANE];
            } else {
                bf16x8 pxv = *(const bf16x8*)(xin_pk +
                    ((size_t)b * PLANE + (size_t)(gx0 + ti) * NYD + (gy0 + col)) * 8);
                #pragma unroll
                for (int c = 0; c < TD; ++c) xv[c] = (float)pxv[c];
            }
            #pragma unroll
            for (int c = 0; c < TD; ++c) {
                const size_t gi = gbase + (size_t)c * PLANE;
                const float vv = xv[c];
                const float g  = gt[gi];
                const float yo = yobs[gi];
                const int   m  = mask[gi];
                mse += (g - vv) * (g - vv);
                float d = vv - yo;
                if (m) dy += d * d;
                // neighbors from bf16 tile (q is ~0.5% of the loss; bf16 fine;
                // zero-halo makes boundary terms vanish automatically)
                float xp1 = (float)*(const __bf16*)(sx + (u * SXW + v + 1) * SX_PS + c * 2);
                float yp1 = (float)*(const __bf16*)(sx + ((u + 1) * SXW + v) * SX_PS + c * 2);
                float tp1 = (c < TD - 1)
                          ? (float)*(const __bf16*)(sx + (u * SXW + v) * SX_PS + (c + 1) * 2)
                          : 0.f;
                q += 6.01f * vv * vv - 2.f * vv * (xp1 + yp1 + tp1);
            }
        }
        #pragma unroll
        for (int off = 32; off > 0; off >>= 1) {
            mse += __shfl_xor(mse, off, 64);
            dy  += __shfl_xor(dy,  off, 64);
            q   += __shfl_xor(q,   off, 64);
        }
        if (lane == 0) {
            const int tile = blockIdx.y * 32 + blockIdx.x;   // 0..511
            float* pp = cpart + (((size_t)b * NPB + tile) * 4 + wv) * 3;
            pp[0] = mse; pp[1] = dy; pp[2] = q;
        }
    }

    // ---- two output tiles (ct = column half), conv body = r8 verbatim ----
    for (int ct = 0; ct < 2; ++ct) {
        f32x4 acc2[4] = {{0.f,0.f,0.f,0.f},{0.f,0.f,0.f,0.f},
                         {0.f,0.f,0.f,0.f},{0.f,0.f,0.f,0.f}};

        for (int half = 0; half < 2; ++half) {
            // ---- conv1 A (weight) frags + bias ----
            bf16x8 A1[2][3];
            f32x4  bias1[2];
            #pragma unroll
            for (int mt = 0; mt < 2; ++mt) {
                bias1[mt] = *(const f32x4*)(b1 + half * 32 + mt * 16 + quad * 4);
                #pragma unroll
                for (int kt = 0; kt < 3; ++kt)
                    A1[mt][kt] = *(const bf16x8*)(W1r +
                        ((size_t)(kt * 64 + half * 32 + mt * 16 + l15) * 32 + quad * 8));
            }
            if (ct || half) __syncthreads();   // prev conv2 reads of sh done

            // ---- conv1: 6 pixel n-tiles per wave ----
            #pragma unroll 2
            for (int nt = 0; nt < 6; ++nt) {
                const int ntg = wv * 6 + nt;
                const int p   = ntg * 16 + l15;   // pixel in padded 384 n-space
                const int pc  = (p < 324) ? p : 323;  // clamp pad lanes
                const int i   = pc / 18;
                const int j   = pc - 18 * i;
                const int pb  = (i * SXW + j + ct * 16) * SX_PS;
                bf16x8 Bx[3];
                #pragma unroll
                for (int kt = 0; kt < 3; ++kt) {
                    int tap = kt * 4 + quad;
                    if (tap > 8) tap = 8;     // pad taps: weights zero, clamp addr
                    Bx[kt] = *(const bf16x8*)(sx + pb +
                              ((tap / 3) * SXW + tap % 3) * SX_PS);
                }
                #pragma unroll
                for (int mt = 0; mt < 2; ++mt) {
                    f32x4 a = {0.f, 0.f, 0.f, 0.f};
                    #pragma unroll
                    for (int kt = 0; kt < 3; ++kt)
                        a = __builtin_amdgcn_mfma_f32_16x16x32_bf16(
                                A1[mt][kt], Bx[kt], a, 0, 0, 0);
                    if (p < 324) {
                        bf16x4 hv;
                        #pragma unroll
                        for (int r = 0; r < 4; ++r)
                            hv[r] = (__bf16)fmaxf(a[r] + bias1[mt][r], 0.f);
                        *(bf16x4*)(sh + p * SH_PS + (mt * 16 + quad * 4) * 2) = hv;
                    }
                }
            }
            __syncthreads();

            // ---- conv2: rolling 6-row x 3-shift window ----
            bf16x8 A2[9];
            #pragma unroll
            for (int tap = 0; tap < 9; ++tap)
                A2[tap] = *(const bf16x8*)(W2r +
                    ((size_t)((half * 9 + tap) * 16 + l15) * 32 + quad * 8));

            const int shbase = (wv * 4 * 18 + l15) * SH_PS + quad * 16;
            bf16x8 R[6][3];
            #pragma unroll
            for (int rr = 0; rr < 3; ++rr)
                #pragma unroll
                for (int tx = 0; tx < 3; ++tx)
                    R[rr][tx] = *(const bf16x8*)(sh + shbase + (rr * 18 + tx) * SH_PS);
            #pragma unroll
            for (int m = 0; m < 4; ++m) {
                #pragma unroll
                for (int dy = 0; dy < 3; ++dy)
                    #pragma unroll
                    for (int tx = 0; tx < 3; ++tx)
                        acc2[m] = __builtin_amdgcn_mfma_f32_16x16x32_bf16(
                                      A2[dy * 3 + tx], R[m + dy][tx], acc2[m], 0, 0, 0);
                if (m < 3) {
                    #pragma unroll
                    for (int tx = 0; tx < 3; ++tx)
                        R[m + 3][tx] = *(const bf16x8*)(sh + shbase +
                                                        ((m + 3) * 18 + tx) * SH_PS);
                }
            }
        }

        // ---- epilogue for this tile: D row = out-channel, col = pixel ----
        float b2v[4];
        #pragma unroll
        for (int r = 0; r < 4; ++r) {
            const int ch = quad * 4 + r;
            b2v[r] = (ch < TD) ? b2[ch] : 0.f;
        }
        if constexpr (OUTP == 0) {
            #pragma unroll
            for (int m = 0; m < 4; ++m) {
                const int ti2 = wv * 4 + m;
                const size_t rowoff = (size_t)b * VOL +
                    (size_t)(gx0 + ti2) * NYD + (gy0 + ct * 16 + l15);
                #pragma unroll
                for (int r = 0; r < 4; ++r) {
                    const int ch = quad * 4 + r;
                    if (ch < TD) {
                        const size_t off = rowoff + (size_t)ch * PLANE;
                        float o = acc2[m][r] + b2v[r];
                        if (blend && mask[off]) o = yobs[off];
                        xout[off] = o;
                    }
                }
            }
        } else {
            const float b2_4 = b2[4];
            #pragma unroll
            for (int m = 0; m < 4; ++m) {
                const int ti2 = wv * 4 + m;
                // ch4 of row ti2, col l15 lives in quad-1 lane (16+l15), reg 0.
                const float c4 = __shfl(acc2[m][0], 16 + l15, 64) + b2_4;
                if (quad == 0) {
                    const size_t poff = (size_t)b * VOL +
                        (size_t)(gx0 + ti2) * NYD + (gy0 + ct * 16 + l15);
                    float o[TD];
                    #pragma unroll
                    for (int r = 0; r < 4; ++r) o[r] = acc2[m][r] + b2v[r];
                    o[4] = c4;
                    if (blend) {
                        #pragma unroll
                        for (int ch = 0; ch < TD; ++ch) {
                            const size_t off = poff + (size_t)ch * PLANE;
                            if (mask[off]) o[ch] = yobs[off];
                        }
                    }
                    bf16x8 pk = {(__bf16)o[0], (__bf16)o[1], (__bf16)o[2],
                                 (__bf16)o[3], (__bf16)o[4],
                                 (__bf16)0.f, (__bf16)0.f, (__bf16)0.f};
                    *(bf16x8*)(xout_pk + ((size_t)b * PLANE +
                        (size_t)(gx0 + ti2) * NYD + (gy0 + ct * 16 + l15)) * 8) = pk;
                }
            }
        }
    }
}

// ---------------------------------------------------------------------------
// Standalone cost (for x5 only). Grid (NPB, BD); per-wave partials.
// ---------------------------------------------------------------------------
__global__ __launch_bounds__(256)
void cost_kernel(const float* __restrict__ x, const float* __restrict__ gt,
                 const float* __restrict__ yobs, const int* __restrict__ mask,
                 float* __restrict__ partial)
{
    const int b  = blockIdx.y;
    const size_t bbase = (size_t)b * VOL;

    float mse = 0.f, dy = 0.f, q = 0.f;
    for (int idx = blockIdx.x * 256 + threadIdx.x; idx < VOL; idx += NPB * 256) {
        const size_t gi = bbase + idx;
        const int t   = idx / PLANE;
        const int rem = idx - t * PLANE;
        const int i   = rem / NYD;
        const int j   = rem - i * NYD;

        const float v  = x[gi];
        const float g  = gt[gi];
        const float yo = yobs[gi];
        const int   m  = mask[gi];

        mse += (g - v) * (g - v);
        float d = v - yo;
        if (m) dy += d * d;
        float qq = 6.01f * v * v;
        if (t < TD - 1)  qq -= 2.f * v * x[gi + PLANE];
        if (i < NXD - 1) qq -= 2.f * v * x[gi + NYD];
        if (j < NYD - 1) qq -= 2.f * v * x[gi + 1];
        q += qq;
    }

    #pragma unroll
    for (int off = 32; off > 0; off >>= 1) {
        mse += __shfl_xor(mse, off, 64);
        dy  += __shfl_xor(dy,  off, 64);
        q   += __shfl_xor(q,   off, 64);
    }
    const int wave = threadIdx.x >> 6;
    const int lane = threadIdx.x & 63;
    if (lane == 0) {
        float* p = partial + (((size_t)b * NPB + blockIdx.x) * 4 + wave) * 3;
        p[0] = mse; p[1] = dy; p[2] = q;
    }
}

// cpart layout: [row r=0..4][b=0..3][NPB*4=2048][3].  out cmp_loss [B=4][5][2].
__global__ __launch_bounds__(256)
void finalize_kernel(const float* __restrict__ cpart,
                     float* __restrict__ out)
{
    const int r = blockIdx.x / BD;
    const int b = blockIdx.x - r * BD;
    const float* base = cpart + ((size_t)r * BD + b) * (NPB * 4) * 3;
    float mse = 0.f, dy = 0.f, q = 0.f;
    for (int k = threadIdx.x; k < NPB * 4; k += 256) {
        mse += base[k * 3 + 0];
        dy  += base[k * 3 + 1];
        q   += base[k * 3 + 2];
    }
    #pragma unroll
    for (int off = 32; off > 0; off >>= 1) {
        mse += __shfl_xor(mse, off, 64);
        dy  += __shfl_xor(dy,  off, 64);
        q   += __shfl_xor(q,   off, 64);
    }
    __shared__ float red[3][4];
    const int wave = threadIdx.x >> 6;
    const int lane = threadIdx.x & 63;
    if (lane == 0) { red[0][wave] = mse; red[1][wave] = dy; red[2][wave] = q; }
    __syncthreads();
    if (threadIdx.x == 0) {
        float m  = red[0][0] + red[0][1] + red[0][2] + red[0][3];
        float d  = red[1][0] + red[1][1] + red[1][2] + red[1][3];
        float qq = red[2][0] + red[2][1] + red[2][2] + red[2][3];
        out[b * 10 + r * 2 + 0] = m / (float)VOL;
        out[b * 10 + r * 2 + 1] = 1000.f * d + qq;
    }
}

extern "C" void kernel_launch(void* const* d_in, const int* in_sizes, int n_in,
                              void* d_out, int out_size, void* d_ws, size_t ws_size,
                              hipStream_t stream)
{
    const float* gt   = (const float*)d_in[0];
    const float* x0   = (const float*)d_in[1];
    const float* yobs = (const float*)d_in[2];
    const int*   mask = (const int*)d_in[3];
    const float* W1   = (const float*)d_in[4];
    const float* b1   = (const float*)d_in[5];
    const float* W2   = (const float*)d_in[6];
    const float* b2   = (const float*)d_in[7];

    float* out_x    = (float*)d_out;
    float* out_loss = out_x + (size_t)BD * VOL;

    float* wsA      = (float*)d_ws;                   // packed ping (16.8 MB)
    float* cpart    = wsA + (size_t)BD * VOL;         // 5*4*2048*3 floats
    __bf16* W1r     = (__bf16*)(cpart + 5 * BD * (NPB * 4) * 3);
    __bf16* W2r     = W1r + W1R_ELEMS;
    const size_t PROW = (size_t)BD * (NPB * 4) * 3;   // per-row stride

    // Packed intermediate buffers: 4*262144*16 B = 16.8 MB each.
    // Pong aliases the out_x region (dead until iter 4 rewrites it fp32):
    //   x1 -> Pout, x2 -> Pws, x3 -> Pout, x4 -> Pws, x5 -> out_x (fp32).
    __bf16* Pout = (__bf16*)out_x;
    __bf16* Pws  = (__bf16*)wsA;

    dim3 pgrid(NXD / 16, NYD / 32, BD), pblock(256);
    dim3 cgrid(NPB, BD), cblock(256);

    prep_weights<<<dim3(60), dim3(256), 0, stream>>>(W1, W2, W1r, W2r);

    phi_mfma<0,1><<<pgrid, pblock, 0, stream>>>(x0, nullptr, W1r, W2r, b1, b2,
        gt, yobs, mask, nullptr, Pout, cpart + 0 * PROW, 1);
    phi_mfma<1,1><<<pgrid, pblock, 0, stream>>>(nullptr, Pout, W1r, W2r, b1, b2,
        gt, yobs, mask, nullptr, Pws,  cpart + 1 * PROW, 1);
    phi_mfma<1,1><<<pgrid, pblock, 0, stream>>>(nullptr, Pws,  W1r, W2r, b1, b2,
        gt, yobs, mask, nullptr, Pout, cpart + 2 * PROW, 1);
    phi_mfma<1,1><<<pgrid, pblock, 0, stream>>>(nullptr, Pout, W1r, W2r, b1, b2,
        gt, yobs, mask, nullptr, Pws,  cpart + 3 * PROW, 1);
    // x5 = phi(x4), no blend, fp32 output (cost_kernel + harness consumer)
    phi_mfma<1,0><<<pgrid, pblock, 0, stream>>>(nullptr, Pws,  W1r, W2r, b1, b2,
        gt, yobs, mask, out_x, nullptr, nullptr, 0);
    // cost(x5) -> row 4
    cost_kernel<<<cgrid, cblock, 0, stream>>>(out_x, gt, yobs, mask, cpart + 4 * PROW);

    finalize_kernel<<<dim3(5 * BD), dim3(256), 0, stream>>>(cpart, out_loss);
}

// Round 10
// 543.904 us; speedup vs baseline: 1.2999x; 1.2999x over previous
//
#include <hip/hip_runtime.h>
#include <hip/hip_bf16.h>

#define NXD 512
#define NYD 512
#define TD 5
#define BD 4
#define HIDD 64
#define PLANE (NXD*NYD)      /* 262144 */
#define VOL (TD*PLANE)       /* 1310720 */
#define CBLK 1024            /* cost blocks per batch (matches phi grid) */

typedef __bf16 bf16x8 __attribute__((ext_vector_type(8)));
typedef __bf16 bf16x4 __attribute__((ext_vector_type(4)));
typedef float  f32x4  __attribute__((ext_vector_type(4)));

// LDS strides: sx 16 B/pixel; sh 80 B/pixel (group stride 5, coprime with 8).
#define SX_PS 16
#define SH_PS 80

// W1r: [kt=3][ch=64][32 bf16]   k = tap*8 + c8   (taps 9..11 zero-padded)
// W2r: [h=2][tap=9][out=16][32] k(within half) = c32; out 5..15 zero
#define W1R_ELEMS (3*64*32)   /* 6144 */
#define W2R_ELEMS (2*9*16*32) /* 9216 */

__global__ __launch_bounds__(256)
void prep_weights(const float* __restrict__ W1, const float* __restrict__ W2,
                  __bf16* __restrict__ W1r, __bf16* __restrict__ W2r)
{
    int id = blockIdx.x * 256 + threadIdx.x;
    if (id < W1R_ELEMS) {
        int kt  = id >> 11;
        int rem = id & 2047;
        int n   = rem >> 5;
        int kk  = rem & 31;
        int k   = kt * 32 + kk;
        int tap = k >> 3, c = k & 7;
        float v = 0.f;
        if (tap <= 8 && c < 5)
            v = W1[(n * 5 + c) * 9 + tap];      // W1 [64][5][3][3]
        W1r[id] = (__bf16)v;
    } else if (id < W1R_ELEMS + W2R_ELEMS) {
        int id2 = id - W1R_ELEMS;
        int h    = id2 / 4608;
        int rem  = id2 - h * 4608;
        int tap  = rem >> 9;
        int rem2 = rem & 511;
        int n    = rem2 >> 5;
        int c    = rem2 & 31;
        float v = 0.f;
        if (n < 5)
            v = W2[(n * HIDD + h * 32 + c) * 9 + tap];  // W2 [5][64][3][3]
        W2r[id2] = (__bf16)v;
    }
}

// ---------------------------------------------------------------------------
// Fused phi (+ optional cost of its INPUT tile).  r8 kernel (543.7us) —
// UNTOUCHED.  Intermediates x1..x4 carried as PACKED bf16x8 per pixel
// ([b][x][y][8], 5 ch + 3 pad, 16 B):
//  * INP=1: stage = ONE global_load_dwordx4 per pixel; cost reads its 5
//    channels with one 16-B load.
//  * OUTP=1: epilogue packs per-pixel via one __shfl (ch4 from quad 1) and
//    stores 16 B from quad-0 lanes.
//  * Conv results BIT-IDENTICAL to the r4 fp32-carried version.
// LDS = 6400 + 25920 = 32320 -> 32768 -> 5 blocks/CU.
// ---------------------------------------------------------------------------
template<int INP, int OUTP>
__global__ __launch_bounds__(256, 4)
void phi_mfma(const float* __restrict__ xin,
              const __bf16* __restrict__ xin_pk,
              const __bf16* __restrict__ W1r, const __bf16* __restrict__ W2r,
              const float* __restrict__ b1, const float* __restrict__ b2,
              const float* __restrict__ gt, const float* __restrict__ yobs,
              const int* __restrict__ mask,
              float* __restrict__ xout, __bf16* __restrict__ xout_pk,
              float* __restrict__ cpart, int blend)
{
    __shared__ __align__(16) char sx[400 * SX_PS];  // 6400 B (20x20 tile)
    __shared__ __align__(16) char sh[324 * SH_PS];  // 25920 B

    const int tid   = threadIdx.x;
    const int wv    = tid >> 6;
    const int lane  = tid & 63;
    const int l15   = lane & 15;
    const int quad  = lane >> 4;
    const int b     = blockIdx.z;
    const int gx0   = blockIdx.x * 16;
    const int gy0   = blockIdx.y * 16;

    // ---- stage x tile 20x20 (halo 2): one b128 write per pixel ----
    for (int p = tid; p < 400; p += 256) {
        const int u  = p / 20;
        const int v  = p - u * 20;
        const int gx = gx0 + u - 2;
        const int gy = gy0 + v - 2;
        bf16x8 pix = {(__bf16)0.f,(__bf16)0.f,(__bf16)0.f,(__bf16)0.f,
                      (__bf16)0.f,(__bf16)0.f,(__bf16)0.f,(__bf16)0.f};
        if (gx >= 0 && gx < NXD && gy >= 0 && gy < NYD) {
            if constexpr (INP == 0) {
                const float* src = xin + (size_t)b * VOL + (size_t)gx * NYD + gy;
                #pragma unroll
                for (int c = 0; c < TD; ++c) pix[c] = (__bf16)src[(size_t)c * PLANE];
            } else {
                pix = *(const bf16x8*)(xin_pk +
                        ((size_t)b * PLANE + (size_t)gx * NYD + gy) * 8);
            }
        }
        *(bf16x8*)(sx + p * SX_PS) = pix;
    }
    __syncthreads();

    // ---- fused cost of the INPUT x (rows 0..3) ----
    if (cpart) {
        const int ti = tid >> 4, tj = tid & 15;
        const int u  = ti + 2,  v  = tj + 2;
        const size_t gbase = (size_t)b * VOL + (size_t)(gx0 + ti) * NYD + (gy0 + tj);
        float xv[TD];
        if constexpr (INP == 0) {
            #pragma unroll
            for (int c = 0; c < TD; ++c) xv[c] = xin[gbase + (size_t)c * PLANE];
        } else {
            bf16x8 pxv = *(const bf16x8*)(xin_pk +
                ((size_t)b * PLANE + (size_t)(gx0 + ti) * NYD + (gy0 + tj)) * 8);
            #pragma unroll
            for (int c = 0; c < TD; ++c) xv[c] = (float)pxv[c];
        }
        float mse = 0.f, dy = 0.f, q = 0.f;
        #pragma unroll
        for (int c = 0; c < TD; ++c) {
            const size_t gi = gbase + (size_t)c * PLANE;
            const float vv = xv[c];
            const float g  = gt[gi];
            const float yo = yobs[gi];
            const int   m  = mask[gi];
            mse += (g - vv) * (g - vv);
            float d = vv - yo;
            if (m) dy += d * d;
            // neighbors from bf16 tile (q is ~0.5% of the loss; bf16 is fine;
            // zero-halo makes boundary terms vanish automatically)
            float xp1 = (float)*(const __bf16*)(sx + (u * 20 + v + 1) * SX_PS + c * 2);
            float yp1 = (float)*(const __bf16*)(sx + ((u + 1) * 20 + v) * SX_PS + c * 2);
            float tp1 = (c < TD - 1)
                      ? (float)*(const __bf16*)(sx + (u * 20 + v) * SX_PS + (c + 1) * 2)
                      : 0.f;
            q += 6.01f * vv * vv - 2.f * vv * (xp1 + yp1 + tp1);
        }
        #pragma unroll
        for (int off = 32; off > 0; off >>= 1) {
            mse += __shfl_xor(mse, off, 64);
            dy  += __shfl_xor(dy,  off, 64);
            q   += __shfl_xor(q,   off, 64);
        }
        if (lane == 0) {
            float* pp = cpart + (((size_t)b * 1024 + blockIdx.y * 32 + blockIdx.x) * 4 + wv) * 3;
            pp[0] = mse; pp[1] = dy; pp[2] = q;
        }
    }

    f32x4 acc2[4] = {{0.f,0.f,0.f,0.f},{0.f,0.f,0.f,0.f},
                     {0.f,0.f,0.f,0.f},{0.f,0.f,0.f,0.f}};

    for (int half = 0; half < 2; ++half) {
        // ---- conv1 A (weight) frags + bias ----
        bf16x8 A1[2][3];
        f32x4  bias1[2];
        #pragma unroll
        for (int mt = 0; mt < 2; ++mt) {
            bias1[mt] = *(const f32x4*)(b1 + half * 32 + mt * 16 + quad * 4);
            #pragma unroll
            for (int kt = 0; kt < 3; ++kt)
                A1[mt][kt] = *(const bf16x8*)(W1r +
                    ((size_t)(kt * 64 + half * 32 + mt * 16 + l15) * 32 + quad * 8));
        }
        if (half) __syncthreads();   // prev conv2 reads of sh done

        // ---- conv1: 6 pixel n-tiles per wave ----
        #pragma unroll 2
        for (int nt = 0; nt < 6; ++nt) {
            const int ntg = wv * 6 + nt;
            const int p   = ntg * 16 + l15;   // pixel in padded 384 n-space
            const int pc  = (p < 324) ? p : 323;  // clamp pad lanes (write-guarded)
            const int i   = pc / 18;
            const int j   = pc - 18 * i;
            const int pb  = (i * 20 + j) * SX_PS;
            bf16x8 Bx[3];
            #pragma unroll
            for (int kt = 0; kt < 3; ++kt) {
                int tap = kt * 4 + quad;
                if (tap > 8) tap = 8;         // pad taps: weights zero, clamp addr
                Bx[kt] = *(const bf16x8*)(sx + pb + ((tap / 3) * 20 + tap % 3) * SX_PS);
            }
            #pragma unroll
            for (int mt = 0; mt < 2; ++mt) {
                f32x4 a = {0.f, 0.f, 0.f, 0.f};
                #pragma unroll
                for (int kt = 0; kt < 3; ++kt)
                    a = __builtin_amdgcn_mfma_f32_16x16x32_bf16(
                            A1[mt][kt], Bx[kt], a, 0, 0, 0);
                if (p < 324) {
                    bf16x4 hv;
                    #pragma unroll
                    for (int r = 0; r < 4; ++r)
                        hv[r] = (__bf16)fmaxf(a[r] + bias1[mt][r], 0.f);
                    *(bf16x4*)(sh + p * SH_PS + (mt * 16 + quad * 4) * 2) = hv;
                }
            }
        }
        __syncthreads();

        // ---- conv2: rolling 6-row x 3-shift window ----
        bf16x8 A2[9];
        #pragma unroll
        for (int tap = 0; tap < 9; ++tap)
            A2[tap] = *(const bf16x8*)(W2r +
                ((size_t)((half * 9 + tap) * 16 + l15) * 32 + quad * 8));

        const int shbase = (wv * 4 * 18 + l15) * SH_PS + quad * 16;
        bf16x8 R[6][3];
        #pragma unroll
        for (int rr = 0; rr < 3; ++rr)
            #pragma unroll
            for (int tx = 0; tx < 3; ++tx)
                R[rr][tx] = *(const bf16x8*)(sh + shbase + (rr * 18 + tx) * SH_PS);
        #pragma unroll
        for (int m = 0; m < 4; ++m) {
            #pragma unroll
            for (int dy = 0; dy < 3; ++dy)
                #pragma unroll
                for (int tx = 0; tx < 3; ++tx)
                    acc2[m] = __builtin_amdgcn_mfma_f32_16x16x32_bf16(
                                  A2[dy * 3 + tx], R[m + dy][tx], acc2[m], 0, 0, 0);
            if (m < 3) {
                #pragma unroll
                for (int tx = 0; tx < 3; ++tx)
                    R[m + 3][tx] = *(const bf16x8*)(sh + shbase +
                                                    ((m + 3) * 18 + tx) * SH_PS);
            }
        }
    }

    // ---- epilogue: D row = out-channel, col = pixel ----
    float b2v[4];
    #pragma unroll
    for (int r = 0; r < 4; ++r) {
        const int ch = quad * 4 + r;
        b2v[r] = (ch < TD) ? b2[ch] : 0.f;
    }
    if constexpr (OUTP == 0) {
        #pragma unroll
        for (int m = 0; m < 4; ++m) {
            const int ti2 = wv * 4 + m;
            const size_t rowoff = (size_t)b * VOL + (size_t)(gx0 + ti2) * NYD + (gy0 + l15);
            #pragma unroll
            for (int r = 0; r < 4; ++r) {
                const int ch = quad * 4 + r;
                if (ch < TD) {
                    const size_t off = rowoff + (size_t)ch * PLANE;
                    float o = acc2[m][r] + b2v[r];
                    if (blend && mask[off]) o = yobs[off];
                    xout[off] = o;
                }
            }
        }
    } else {
        const float b2_4 = b2[4];
        #pragma unroll
        for (int m = 0; m < 4; ++m) {
            const int ti2 = wv * 4 + m;
            // ch4 of row ti2, col l15 lives in quad-1 lane (16+l15), reg 0.
            const float c4 = __shfl(acc2[m][0], 16 + l15, 64) + b2_4;
            if (quad == 0) {
                const size_t poff = (size_t)b * VOL +
                                    (size_t)(gx0 + ti2) * NYD + (gy0 + l15);
                float o[TD];
                #pragma unroll
                for (int r = 0; r < 4; ++r) o[r] = acc2[m][r] + b2v[r];
                o[4] = c4;
                if (blend) {
                    #pragma unroll
                    for (int ch = 0; ch < TD; ++ch) {
                        const size_t off = poff + (size_t)ch * PLANE;
                        if (mask[off]) o[ch] = yobs[off];
                    }
                }
                bf16x8 pk = {(__bf16)o[0], (__bf16)o[1], (__bf16)o[2],
                             (__bf16)o[3], (__bf16)o[4],
                             (__bf16)0.f, (__bf16)0.f, (__bf16)0.f};
                *(bf16x8*)(xout_pk + ((size_t)b * PLANE +
                    (size_t)(gx0 + ti2) * NYD + (gy0 + l15)) * 8) = pk;
            }
        }
    }
}

// ---------------------------------------------------------------------------
// Standalone cost (for x5 only), PIXEL-parallel: 1 pixel (5 channels) per
// thread; grid (1024, BD) x 256 = exactly PLANE px per batch.  t-neighbors
// in-register, y-neighbor via shfl_down (lanes are j-consecutive; lane 63
// falls back to a guarded load), x-neighbor guarded load.  ~21 load events
// per 5 elements vs 35 in the element-parallel version; all fp32 (numerics
// = reference up to summation order).
// ---------------------------------------------------------------------------
__global__ __launch_bounds__(256)
void cost_kernel(const float* __restrict__ x, const float* __restrict__ gt,
                 const float* __restrict__ yobs, const int* __restrict__ mask,
                 float* __restrict__ partial)
{
    const int b    = blockIdx.y;
    const int lane = threadIdx.x & 63;
    const int wave = threadIdx.x >> 6;
    const int px   = blockIdx.x * 256 + threadIdx.x;   // 0..262143
    const int i    = px >> 9;           // row (x index)
    const int j    = px & 511;          // col (y index)
    const size_t gbase = (size_t)b * VOL + px;

    float xv[TD];
    #pragma unroll
    for (int c = 0; c < TD; ++c) xv[c] = x[gbase + (size_t)c * PLANE];

    float mse = 0.f, dy = 0.f, q = 0.f;
    #pragma unroll
    for (int c = 0; c < TD; ++c) {
        const size_t gi = gbase + (size_t)c * PLANE;
        const float v  = xv[c];
        const float g  = gt[gi];
        const float yo = yobs[gi];
        const int   m  = mask[gi];

        mse += (g - v) * (g - v);
        float d = v - yo;
        if (m) dy += d * d;

        float tp1 = (c < TD - 1) ? xv[c + 1] : 0.f;            // t-neighbor
        float yp1 = __shfl_down(xv[c], 1, 64);                 // j-neighbor
        if (lane == 63) yp1 = (j < NYD - 1) ? x[gi + 1] : 0.f;
        float xp1 = (i < NXD - 1) ? x[gi + NYD] : 0.f;         // i-neighbor
        q += 6.01f * v * v - 2.f * v * (tp1 + yp1 + xp1);
    }

    #pragma unroll
    for (int off = 32; off > 0; off >>= 1) {
        mse += __shfl_xor(mse, off, 64);
        dy  += __shfl_xor(dy,  off, 64);
        q   += __shfl_xor(q,   off, 64);
    }
    if (lane == 0) {
        float* p = partial + (((size_t)b * CBLK + blockIdx.x) * 4 + wave) * 3;
        p[0] = mse; p[1] = dy; p[2] = q;
    }
}

// cpart layout: [row r=0..4][b=0..3][4096][3].  out cmp_loss [B=4][5][2].
__global__ __launch_bounds__(256)
void finalize_kernel(const float* __restrict__ cpart,
                     float* __restrict__ out)
{
    const int r = blockIdx.x / BD;
    const int b = blockIdx.x - r * BD;
    const float* base = cpart + ((size_t)r * BD + b) * 4096 * 3;
    float mse = 0.f, dy = 0.f, q = 0.f;
    for (int k = threadIdx.x; k < 4096; k += 256) {
        mse += base[k * 3 + 0];
        dy  += base[k * 3 + 1];
        q   += base[k * 3 + 2];
    }
    #pragma unroll
    for (int off = 32; off > 0; off >>= 1) {
        mse += __shfl_xor(mse, off, 64);
        dy  += __shfl_xor(dy,  off, 64);
        q   += __shfl_xor(q,   off, 64);
    }
    __shared__ float red[3][4];
    const int wave = threadIdx.x >> 6;
    const int lane = threadIdx.x & 63;
    if (lane == 0) { red[0][wave] = mse; red[1][wave] = dy; red[2][wave] = q; }
    __syncthreads();
    if (threadIdx.x == 0) {
        float m  = red[0][0] + red[0][1] + red[0][2] + red[0][3];
        float d  = red[1][0] + red[1][1] + red[1][2] + red[1][3];
        float qq = red[2][0] + red[2][1] + red[2][2] + red[2][3];
        out[b * 10 + r * 2 + 0] = m / (float)VOL;
        out[b * 10 + r * 2 + 1] = 1000.f * d + qq;
    }
}

extern "C" void kernel_launch(void* const* d_in, const int* in_sizes, int n_in,
                              void* d_out, int out_size, void* d_ws, size_t ws_size,
                              hipStream_t stream)
{
    const float* gt   = (const float*)d_in[0];
    const float* x0   = (const float*)d_in[1];
    const float* yobs = (const float*)d_in[2];
    const int*   mask = (const int*)d_in[3];
    const float* W1   = (const float*)d_in[4];
    const float* b1   = (const float*)d_in[5];
    const float* W2   = (const float*)d_in[6];
    const float* b2   = (const float*)d_in[7];

    float* out_x    = (float*)d_out;
    float* out_loss = out_x + (size_t)BD * VOL;

    float* wsA      = (float*)d_ws;                   // packed ping (16.8 MB)
    float* cpart    = wsA + (size_t)BD * VOL;         // 5*4*4096*3 floats
    __bf16* W1r     = (__bf16*)(cpart + 5 * BD * 4096 * 3);
    __bf16* W2r     = W1r + W1R_ELEMS;
    const size_t PROW = (size_t)BD * 4096 * 3;        // per-row stride

    // Packed intermediate buffers: 4*262144*16 B = 16.8 MB each.
    // Pong aliases the out_x region (dead until iter 4 rewrites it fp32):
    //   x1 -> Pout, x2 -> Pws, x3 -> Pout, x4 -> Pws, x5 -> out_x (fp32).
    __bf16* Pout = (__bf16*)out_x;
    __bf16* Pws  = (__bf16*)wsA;

    dim3 pgrid(NXD / 16, NYD / 16, BD), pblock(256);
    dim3 cgrid(CBLK, BD), cblock(256);

    prep_weights<<<dim3(60), dim3(256), 0, stream>>>(W1, W2, W1r, W2r);

    phi_mfma<0,1><<<pgrid, pblock, 0, stream>>>(x0, nullptr, W1r, W2r, b1, b2,
        gt, yobs, mask, nullptr, Pout, cpart + 0 * PROW, 1);
    phi_mfma<1,1><<<pgrid, pblock, 0, stream>>>(nullptr, Pout, W1r, W2r, b1, b2,
        gt, yobs, mask, nullptr, Pws,  cpart + 1 * PROW, 1);
    phi_mfma<1,1><<<pgrid, pblock, 0, stream>>>(nullptr, Pws,  W1r, W2r, b1, b2,
        gt, yobs, mask, nullptr, Pout, cpart + 2 * PROW, 1);
    phi_mfma<1,1><<<pgrid, pblock, 0, stream>>>(nullptr, Pout, W1r, W2r, b1, b2,
        gt, yobs, mask, nullptr, Pws,  cpart + 3 * PROW, 1);
    // x5 = phi(x4), no blend, fp32 output (cost_kernel + harness consumer)
    phi_mfma<1,0><<<pgrid, pblock, 0, stream>>>(nullptr, Pws,  W1r, W2r, b1, b2,
        gt, yobs, mask, out_x, nullptr, nullptr, 0);
    // cost(x5) -> row 4
    cost_kernel<<<cgrid, cblock, 0, stream>>>(out_x, gt, yobs, mask, cpart + 4 * PROW);

    finalize_kernel<<<dim3(5 * BD), dim3(256), 0, stream>>>(cpart, out_loss);
}

// Round 11
// 475.103 us; speedup vs baseline: 1.4881x; 1.1448x over previous
//
#include <hip/hip_runtime.h>
#include <hip/hip_bf16.h>

#define NXD 512
#define NYD 512
#define TD 5
#define BD 4
#define HIDD 64
#define PLANE (NXD*NYD)      /* 262144 */
#define VOL (TD*PLANE)       /* 1310720 */
#define CBLK 1024            /* cost blocks per batch (matches phi grid) */

typedef __bf16 bf16x8 __attribute__((ext_vector_type(8)));
typedef __bf16 bf16x4 __attribute__((ext_vector_type(4)));
typedef float  f32x4  __attribute__((ext_vector_type(4)));

// LDS strides: sx 16 B/pixel; sh 80 B/pixel (group stride 5, coprime with 8).
#define SX_PS 16
#define SH_PS 80

// W1r: [kt=3][ch=64][32 bf16]   k = tap*8 + c8   (taps 9..11 zero-padded)
// W2r: [h=2][tap=9][out=16][32] k(within half) = c32; out 5..15 zero
#define W1R_ELEMS (3*64*32)   /* 6144 */
#define W2R_ELEMS (2*9*16*32) /* 9216 */

// gtm: per-pixel packed aux, 16 B = uint4 { bf16 gt0|gt1, gt2|gt3, gt4|0, maskbits }
__device__ __forceinline__ float bfu(unsigned u)   // low 16 bits as bf16 -> f32
{
    union { float f; unsigned x; } t; t.x = u << 16; return t.f;
}
__device__ __forceinline__ unsigned bpack(float a, float b)
{
    __bf16 ba = (__bf16)a, bb = (__bf16)b;
    return (unsigned)__builtin_bit_cast(unsigned short, ba) |
           ((unsigned)__builtin_bit_cast(unsigned short, bb) << 16);
}

__global__ __launch_bounds__(256)
void prep_weights(const float* __restrict__ W1, const float* __restrict__ W2,
                  __bf16* __restrict__ W1r, __bf16* __restrict__ W2r)
{
    int id = blockIdx.x * 256 + threadIdx.x;
    if (id < W1R_ELEMS) {
        int kt  = id >> 11;
        int rem = id & 2047;
        int n   = rem >> 5;
        int kk  = rem & 31;
        int k   = kt * 32 + kk;
        int tap = k >> 3, c = k & 7;
        float v = 0.f;
        if (tap <= 8 && c < 5)
            v = W1[(n * 5 + c) * 9 + tap];      // W1 [64][5][3][3]
        W1r[id] = (__bf16)v;
    } else if (id < W1R_ELEMS + W2R_ELEMS) {
        int id2 = id - W1R_ELEMS;
        int h    = id2 / 4608;
        int rem  = id2 - h * 4608;
        int tap  = rem >> 9;
        int rem2 = rem & 511;
        int n    = rem2 >> 5;
        int c    = rem2 & 31;
        float v = 0.f;
        if (n < 5)
            v = W2[(n * HIDD + h * 32 + c) * 9 + tap];  // W2 [5][64][3][3]
        W2r[id2] = (__bf16)v;
    }
}

// ---------------------------------------------------------------------------
// Fused phi (+ optional cost of its INPUT tile).  r8/r10 kernel (543.7us);
// conv pipeline UNTOUCHED.  New in r11 (cost/epilogue sections only):
//  * INP=0 cost (row 0, all-fp32, exact): additionally packs gt5(bf16) +
//    maskbits into the 16-B/px gtm buffer (one uint4 store).
//  * INP=1 cost (rows 1..3): dy == 0 EXACTLY (blend makes x_k = yobs at
//    masked px in the reference) -> hardcoded 0; gt from gtm.  Loads drop
//    from 1 vec + 15 scalars to 2 vec.
//  * OUTP=1 epilogue blend: maskbits from gtm (1 load replaces 5 scalars);
//    yobs scalar loads only for masked channels, as before.
// LDS = 6400 + 25920 = 32320 -> 32768 -> 5 blocks/CU.
// ---------------------------------------------------------------------------
template<int INP, int OUTP>
__global__ __launch_bounds__(256, 4)
void phi_mfma(const float* __restrict__ xin,
              const __bf16* __restrict__ xin_pk,
              const __bf16* __restrict__ W1r, const __bf16* __restrict__ W2r,
              const float* __restrict__ b1, const float* __restrict__ b2,
              const float* __restrict__ gt, const float* __restrict__ yobs,
              const int* __restrict__ mask, unsigned* __restrict__ gtm,
              float* __restrict__ xout, __bf16* __restrict__ xout_pk,
              float* __restrict__ cpart, int blend)
{
    __shared__ __align__(16) char sx[400 * SX_PS];  // 6400 B (20x20 tile)
    __shared__ __align__(16) char sh[324 * SH_PS];  // 25920 B

    const int tid   = threadIdx.x;
    const int wv    = tid >> 6;
    const int lane  = tid & 63;
    const int l15   = lane & 15;
    const int quad  = lane >> 4;
    const int b     = blockIdx.z;
    const int gx0   = blockIdx.x * 16;
    const int gy0   = blockIdx.y * 16;

    // ---- stage x tile 20x20 (halo 2): one b128 write per pixel ----
    for (int p = tid; p < 400; p += 256) {
        const int u  = p / 20;
        const int v  = p - u * 20;
        const int gx = gx0 + u - 2;
        const int gy = gy0 + v - 2;
        bf16x8 pix = {(__bf16)0.f,(__bf16)0.f,(__bf16)0.f,(__bf16)0.f,
                      (__bf16)0.f,(__bf16)0.f,(__bf16)0.f,(__bf16)0.f};
        if (gx >= 0 && gx < NXD && gy >= 0 && gy < NYD) {
            if constexpr (INP == 0) {
                const float* src = xin + (size_t)b * VOL + (size_t)gx * NYD + gy;
                #pragma unroll
                for (int c = 0; c < TD; ++c) pix[c] = (__bf16)src[(size_t)c * PLANE];
            } else {
                pix = *(const bf16x8*)(xin_pk +
                        ((size_t)b * PLANE + (size_t)gx * NYD + gy) * 8);
            }
        }
        *(bf16x8*)(sx + p * SX_PS) = pix;
    }
    __syncthreads();

    // ---- fused cost of the INPUT x (rows 0..3) ----
    if (cpart) {
        const int ti = tid >> 4, tj = tid & 15;
        const int u  = ti + 2,  v  = tj + 2;
        const size_t pxi = (size_t)b * PLANE + (size_t)(gx0 + ti) * NYD + (gy0 + tj);
        const size_t gbase = (size_t)b * VOL + (size_t)(gx0 + ti) * NYD + (gy0 + tj);
        float mse = 0.f, dy = 0.f, q = 0.f;

        if constexpr (INP == 0) {
            // row 0: all-fp32 (exact); also pack gt+maskbits -> gtm
            float gts[TD]; unsigned mb = 0;
            #pragma unroll
            for (int c = 0; c < TD; ++c) {
                const size_t gi = gbase + (size_t)c * PLANE;
                const float vv = xin[gi];
                const float g  = gt[gi];
                const float yo = yobs[gi];
                const int   m  = mask[gi];
                gts[c] = g;
                if (m) mb |= 1u << c;
                mse += (g - vv) * (g - vv);
                float d = vv - yo;
                if (m) dy += d * d;
                float xp1 = (float)*(const __bf16*)(sx + (u * 20 + v + 1) * SX_PS + c * 2);
                float yp1 = (float)*(const __bf16*)(sx + ((u + 1) * 20 + v) * SX_PS + c * 2);
                float tp1 = (c < TD - 1)
                          ? (float)*(const __bf16*)(sx + (u * 20 + v) * SX_PS + (c + 1) * 2)
                          : 0.f;
                q += 6.01f * vv * vv - 2.f * vv * (xp1 + yp1 + tp1);
            }
            uint4 gv;
            gv.x = bpack(gts[0], gts[1]);
            gv.y = bpack(gts[2], gts[3]);
            gv.z = bpack(gts[4], 0.f);
            gv.w = mb;
            *(uint4*)(gtm + pxi * 4) = gv;
        } else {
            // rows 1..3: x bf16-packed; gt from gtm; dy == 0 exactly.
            bf16x8 pxv = *(const bf16x8*)(xin_pk + pxi * 8);
            const uint4 gv = *(const uint4*)(gtm + pxi * 4);
            float gts[TD];
            gts[0] = bfu(gv.x & 0xffffu); gts[1] = bfu(gv.x >> 16);
            gts[2] = bfu(gv.y & 0xffffu); gts[3] = bfu(gv.y >> 16);
            gts[4] = bfu(gv.z & 0xffffu);
            #pragma unroll
            for (int c = 0; c < TD; ++c) {
                const float vv = (float)pxv[c];
                mse += (gts[c] - vv) * (gts[c] - vv);
                float xp1 = (float)*(const __bf16*)(sx + (u * 20 + v + 1) * SX_PS + c * 2);
                float yp1 = (float)*(const __bf16*)(sx + ((u + 1) * 20 + v) * SX_PS + c * 2);
                float tp1 = (c < TD - 1)
                          ? (float)*(const __bf16*)(sx + (u * 20 + v) * SX_PS + (c + 1) * 2)
                          : 0.f;
                q += 6.01f * vv * vv - 2.f * vv * (xp1 + yp1 + tp1);
            }
        }

        #pragma unroll
        for (int off = 32; off > 0; off >>= 1) {
            mse += __shfl_xor(mse, off, 64);
            dy  += __shfl_xor(dy,  off, 64);
            q   += __shfl_xor(q,   off, 64);
        }
        if (lane == 0) {
            float* pp = cpart + (((size_t)b * 1024 + blockIdx.y * 32 + blockIdx.x) * 4 + wv) * 3;
            pp[0] = mse; pp[1] = dy; pp[2] = q;
        }
    }

    f32x4 acc2[4] = {{0.f,0.f,0.f,0.f},{0.f,0.f,0.f,0.f},
                     {0.f,0.f,0.f,0.f},{0.f,0.f,0.f,0.f}};

    for (int half = 0; half < 2; ++half) {
        // ---- conv1 A (weight) frags + bias ----
        bf16x8 A1[2][3];
        f32x4  bias1[2];
        #pragma unroll
        for (int mt = 0; mt < 2; ++mt) {
            bias1[mt] = *(const f32x4*)(b1 + half * 32 + mt * 16 + quad * 4);
            #pragma unroll
            for (int kt = 0; kt < 3; ++kt)
                A1[mt][kt] = *(const bf16x8*)(W1r +
                    ((size_t)(kt * 64 + half * 32 + mt * 16 + l15) * 32 + quad * 8));
        }
        if (half) __syncthreads();   // prev conv2 reads of sh done

        // ---- conv1: 6 pixel n-tiles per wave ----
        #pragma unroll 2
        for (int nt = 0; nt < 6; ++nt) {
            const int ntg = wv * 6 + nt;
            const int p   = ntg * 16 + l15;   // pixel in padded 384 n-space
            const int pc  = (p < 324) ? p : 323;  // clamp pad lanes (write-guarded)
            const int i   = pc / 18;
            const int j   = pc - 18 * i;
            const int pb  = (i * 20 + j) * SX_PS;
            bf16x8 Bx[3];
            #pragma unroll
            for (int kt = 0; kt < 3; ++kt) {
                int tap = kt * 4 + quad;
                if (tap > 8) tap = 8;         // pad taps: weights zero, clamp addr
                Bx[kt] = *(const bf16x8*)(sx + pb + ((tap / 3) * 20 + tap % 3) * SX_PS);
            }
            #pragma unroll
            for (int mt = 0; mt < 2; ++mt) {
                f32x4 a = {0.f, 0.f, 0.f, 0.f};
                #pragma unroll
                for (int kt = 0; kt < 3; ++kt)
                    a = __builtin_amdgcn_mfma_f32_16x16x32_bf16(
                            A1[mt][kt], Bx[kt], a, 0, 0, 0);
                if (p < 324) {
                    bf16x4 hv;
                    #pragma unroll
                    for (int r = 0; r < 4; ++r)
                        hv[r] = (__bf16)fmaxf(a[r] + bias1[mt][r], 0.f);
                    *(bf16x4*)(sh + p * SH_PS + (mt * 16 + quad * 4) * 2) = hv;
                }
            }
        }
        __syncthreads();

        // ---- conv2: rolling 6-row x 3-shift window ----
        bf16x8 A2[9];
        #pragma unroll
        for (int tap = 0; tap < 9; ++tap)
            A2[tap] = *(const bf16x8*)(W2r +
                ((size_t)((half * 9 + tap) * 16 + l15) * 32 + quad * 8));

        const int shbase = (wv * 4 * 18 + l15) * SH_PS + quad * 16;
        bf16x8 R[6][3];
        #pragma unroll
        for (int rr = 0; rr < 3; ++rr)
            #pragma unroll
            for (int tx = 0; tx < 3; ++tx)
                R[rr][tx] = *(const bf16x8*)(sh + shbase + (rr * 18 + tx) * SH_PS);
        #pragma unroll
        for (int m = 0; m < 4; ++m) {
            #pragma unroll
            for (int dy2 = 0; dy2 < 3; ++dy2)
                #pragma unroll
                for (int tx = 0; tx < 3; ++tx)
                    acc2[m] = __builtin_amdgcn_mfma_f32_16x16x32_bf16(
                                  A2[dy2 * 3 + tx], R[m + dy2][tx], acc2[m], 0, 0, 0);
            if (m < 3) {
                #pragma unroll
                for (int tx = 0; tx < 3; ++tx)
                    R[m + 3][tx] = *(const bf16x8*)(sh + shbase +
                                                    ((m + 3) * 18 + tx) * SH_PS);
            }
        }
    }

    // ---- epilogue: D row = out-channel, col = pixel ----
    float b2v[4];
    #pragma unroll
    for (int r = 0; r < 4; ++r) {
        const int ch = quad * 4 + r;
        b2v[r] = (ch < TD) ? b2[ch] : 0.f;
    }
    if constexpr (OUTP == 0) {
        #pragma unroll
        for (int m = 0; m < 4; ++m) {
            const int ti2 = wv * 4 + m;
            const size_t rowoff = (size_t)b * VOL + (size_t)(gx0 + ti2) * NYD + (gy0 + l15);
            #pragma unroll
            for (int r = 0; r < 4; ++r) {
                const int ch = quad * 4 + r;
                if (ch < TD) {
                    const size_t off = rowoff + (size_t)ch * PLANE;
                    float o = acc2[m][r] + b2v[r];
                    if (blend && mask[off]) o = yobs[off];
                    xout[off] = o;
                }
            }
        }
    } else {
        const float b2_4 = b2[4];
        #pragma unroll
        for (int m = 0; m < 4; ++m) {
            const int ti2 = wv * 4 + m;
            // ch4 of row ti2, col l15 lives in quad-1 lane (16+l15), reg 0.
            const float c4 = __shfl(acc2[m][0], 16 + l15, 64) + b2_4;
            if (quad == 0) {
                const size_t pxo  = (size_t)b * PLANE +
                                    (size_t)(gx0 + ti2) * NYD + (gy0 + l15);
                const size_t poff = (size_t)b * VOL +
                                    (size_t)(gx0 + ti2) * NYD + (gy0 + l15);
                float o[TD];
                #pragma unroll
                for (int r = 0; r < 4; ++r) o[r] = acc2[m][r] + b2v[r];
                o[4] = c4;
                if (blend) {
                    const unsigned mb = ((const uint4*)(gtm + pxo * 4))->w;
                    #pragma unroll
                    for (int ch = 0; ch < TD; ++ch) {
                        if ((mb >> ch) & 1)
                            o[ch] = yobs[poff + (size_t)ch * PLANE];
                    }
                }
                bf16x8 pk = {(__bf16)o[0], (__bf16)o[1], (__bf16)o[2],
                             (__bf16)o[3], (__bf16)o[4],
                             (__bf16)0.f, (__bf16)0.f, (__bf16)0.f};
                *(bf16x8*)(xout_pk + pxo * 8) = pk;
            }
        }
    }
}

// ---------------------------------------------------------------------------
// Standalone cost (for x5 only), PIXEL-parallel (r10) + gtm for gt/maskbits.
// yobs loaded fp32 only at masked channels (dy row 4 is nonzero: x5 unblended).
// ---------------------------------------------------------------------------
__global__ __launch_bounds__(256)
void cost_kernel(const float* __restrict__ x, const unsigned* __restrict__ gtm,
                 const float* __restrict__ yobs,
                 float* __restrict__ partial)
{
    const int b    = blockIdx.y;
    const int lane = threadIdx.x & 63;
    const int wave = threadIdx.x >> 6;
    const int px   = blockIdx.x * 256 + threadIdx.x;   // 0..262143
    const int i    = px >> 9;           // row (x index)
    const int j    = px & 511;          // col (y index)
    const size_t pxi   = (size_t)b * PLANE + px;
    const size_t gbase = (size_t)b * VOL + px;

    float xv[TD];
    #pragma unroll
    for (int c = 0; c < TD; ++c) xv[c] = x[gbase + (size_t)c * PLANE];

    const uint4 gv = *(const uint4*)(gtm + pxi * 4);
    float gts[TD];
    gts[0] = bfu(gv.x & 0xffffu); gts[1] = bfu(gv.x >> 16);
    gts[2] = bfu(gv.y & 0xffffu); gts[3] = bfu(gv.y >> 16);
    gts[4] = bfu(gv.z & 0xffffu);
    const unsigned mb = gv.w;

    float mse = 0.f, dy = 0.f, q = 0.f;
    #pragma unroll
    for (int c = 0; c < TD; ++c) {
        const size_t gi = gbase + (size_t)c * PLANE;
        const float v  = xv[c];
        mse += (gts[c] - v) * (gts[c] - v);
        if ((mb >> c) & 1) {
            float d = v - yobs[gi];
            dy += d * d;
        }
        float tp1 = (c < TD - 1) ? xv[c + 1] : 0.f;            // t-neighbor
        float yp1 = __shfl_down(xv[c], 1, 64);                 // j-neighbor
        if (lane == 63) yp1 = (j < NYD - 1) ? x[gi + 1] : 0.f;
        float xp1 = (i < NXD - 1) ? x[gi + NYD] : 0.f;         // i-neighbor
        q += 6.01f * v * v - 2.f * v * (tp1 + yp1 + xp1);
    }

    #pragma unroll
    for (int off = 32; off > 0; off >>= 1) {
        mse += __shfl_xor(mse, off, 64);
        dy  += __shfl_xor(dy,  off, 64);
        q   += __shfl_xor(q,   off, 64);
    }
    if (lane == 0) {
        float* p = partial + (((size_t)b * CBLK + blockIdx.x) * 4 + wave) * 3;
        p[0] = mse; p[1] = dy; p[2] = q;
    }
}

// cpart layout: [row r=0..4][b=0..3][4096][3].  out cmp_loss [B=4][5][2].
__global__ __launch_bounds__(256)
void finalize_kernel(const float* __restrict__ cpart,
                     float* __restrict__ out)
{
    const int r = blockIdx.x / BD;
    const int b = blockIdx.x - r * BD;
    const float* base = cpart + ((size_t)r * BD + b) * 4096 * 3;
    float mse = 0.f, dy = 0.f, q = 0.f;
    for (int k = threadIdx.x; k < 4096; k += 256) {
        mse += base[k * 3 + 0];
        dy  += base[k * 3 + 1];
        q   += base[k * 3 + 2];
    }
    #pragma unroll
    for (int off = 32; off > 0; off >>= 1) {
        mse += __shfl_xor(mse, off, 64);
        dy  += __shfl_xor(dy,  off, 64);
        q   += __shfl_xor(q,   off, 64);
    }
    __shared__ float red[3][4];
    const int wave = threadIdx.x >> 6;
    const int lane = threadIdx.x & 63;
    if (lane == 0) { red[0][wave] = mse; red[1][wave] = dy; red[2][wave] = q; }
    __syncthreads();
    if (threadIdx.x == 0) {
        float m  = red[0][0] + red[0][1] + red[0][2] + red[0][3];
        float d  = red[1][0] + red[1][1] + red[1][2] + red[1][3];
        float qq = red[2][0] + red[2][1] + red[2][2] + red[2][3];
        out[b * 10 + r * 2 + 0] = m / (float)VOL;
        out[b * 10 + r * 2 + 1] = 1000.f * d + qq;
    }
}

extern "C" void kernel_launch(void* const* d_in, const int* in_sizes, int n_in,
                              void* d_out, int out_size, void* d_ws, size_t ws_size,
                              hipStream_t stream)
{
    const float* gt   = (const float*)d_in[0];
    const float* x0   = (const float*)d_in[1];
    const float* yobs = (const float*)d_in[2];
    const int*   mask = (const int*)d_in[3];
    const float* W1   = (const float*)d_in[4];
    const float* b1   = (const float*)d_in[5];
    const float* W2   = (const float*)d_in[6];
    const float* b2   = (const float*)d_in[7];

    float* out_x    = (float*)d_out;
    float* out_loss = out_x + (size_t)BD * VOL;

    float* wsA      = (float*)d_ws;                   // packed ping (16.8 MB)
    float* cpart    = wsA + (size_t)BD * VOL;         // 5*4*4096*3 floats
    __bf16* W1r     = (__bf16*)(cpart + 5 * BD * 4096 * 3);
    __bf16* W2r     = W1r + W1R_ELEMS;
    unsigned* gtm   = (unsigned*)(W2r + W2R_ELEMS);   // 16 B/px aux (16.8 MB)
    const size_t PROW = (size_t)BD * 4096 * 3;        // per-row stride

    // Packed intermediate buffers: 4*262144*16 B = 16.8 MB each.
    // Pong aliases the out_x region (dead until iter 4 rewrites it fp32):
    //   x1 -> Pout, x2 -> Pws, x3 -> Pout, x4 -> Pws, x5 -> out_x (fp32).
    __bf16* Pout = (__bf16*)out_x;
    __bf16* Pws  = (__bf16*)wsA;

    dim3 pgrid(NXD / 16, NYD / 16, BD), pblock(256);
    dim3 cgrid(CBLK, BD), cblock(256);

    prep_weights<<<dim3(60), dim3(256), 0, stream>>>(W1, W2, W1r, W2r);

    phi_mfma<0,1><<<pgrid, pblock, 0, stream>>>(x0, nullptr, W1r, W2r, b1, b2,
        gt, yobs, mask, gtm, nullptr, Pout, cpart + 0 * PROW, 1);
    phi_mfma<1,1><<<pgrid, pblock, 0, stream>>>(nullptr, Pout, W1r, W2r, b1, b2,
        gt, yobs, mask, gtm, nullptr, Pws,  cpart + 1 * PROW, 1);
    phi_mfma<1,1><<<pgrid, pblock, 0, stream>>>(nullptr, Pws,  W1r, W2r, b1, b2,
        gt, yobs, mask, gtm, nullptr, Pout, cpart + 2 * PROW, 1);
    phi_mfma<1,1><<<pgrid, pblock, 0, stream>>>(nullptr, Pout, W1r, W2r, b1, b2,
        gt, yobs, mask, gtm, nullptr, Pws,  cpart + 3 * PROW, 1);
    // x5 = phi(x4), no blend, fp32 output (cost_kernel + harness consumer)
    phi_mfma<1,0><<<pgrid, pblock, 0, stream>>>(nullptr, Pws,  W1r, W2r, b1, b2,
        gt, yobs, mask, gtm, out_x, nullptr, nullptr, 0);
    // cost(x5) -> row 4
    cost_kernel<<<cgrid, cblock, 0, stream>>>(out_x, gtm, yobs, cpart + 4 * PROW);

    finalize_kernel<<<dim3(5 * BD), dim3(256), 0, stream>>>(cpart, out_loss);
}

// Round 12
// 458.514 us; speedup vs baseline: 1.5420x; 1.0362x over previous
//
#include <hip/hip_runtime.h>
#include <hip/hip_bf16.h>

#define NXD 512
#define NYD 512
#define TD 5
#define BD 4
#define HIDD 64
#define PLANE (NXD*NYD)      /* 262144 */
#define VOL (TD*PLANE)       /* 1310720 */
#define CBLK 1024            /* cost blocks per batch (matches phi grid) */

typedef __bf16 bf16x8 __attribute__((ext_vector_type(8)));
typedef __bf16 bf16x4 __attribute__((ext_vector_type(4)));
typedef float  f32x4  __attribute__((ext_vector_type(4)));

// LDS strides: sx 16 B/pixel; sh 80 B/pixel (group stride 5, coprime with 8).
#define SX_PS 16
#define SH_PS 80

// W1r: [kt=3][ch=64][32 bf16]   k = tap*8 + c8   (taps 9..11 zero-padded)
// W2r: [h=2][tap=9][out=16][32] k(within half) = c32; out 5..15 zero
#define W1R_ELEMS (3*64*32)   /* 6144 */
#define W2R_ELEMS (2*9*16*32) /* 9216 */

// gtm: per-pixel packed aux, 16 B = uint4 { bf16 gt0|gt1, gt2|gt3, gt4|0, maskbits }
// ym : per-pixel packed aux, 16 B = uint4 { bf16 y0|y1,  y2|y3,  y4|mb<<16, 0 }
__device__ __forceinline__ float bfu(unsigned u)   // low 16 bits as bf16 -> f32
{
    union { float f; unsigned x; } t; t.x = u << 16; return t.f;
}
__device__ __forceinline__ unsigned bpack(float a, float b)
{
    __bf16 ba = (__bf16)a, bb = (__bf16)b;
    return (unsigned)__builtin_bit_cast(unsigned short, ba) |
           ((unsigned)__builtin_bit_cast(unsigned short, bb) << 16);
}

__global__ __launch_bounds__(256)
void prep_weights(const float* __restrict__ W1, const float* __restrict__ W2,
                  __bf16* __restrict__ W1r, __bf16* __restrict__ W2r)
{
    int id = blockIdx.x * 256 + threadIdx.x;
    if (id < W1R_ELEMS) {
        int kt  = id >> 11;
        int rem = id & 2047;
        int n   = rem >> 5;
        int kk  = rem & 31;
        int k   = kt * 32 + kk;
        int tap = k >> 3, c = k & 7;
        float v = 0.f;
        if (tap <= 8 && c < 5)
            v = W1[(n * 5 + c) * 9 + tap];      // W1 [64][5][3][3]
        W1r[id] = (__bf16)v;
    } else if (id < W1R_ELEMS + W2R_ELEMS) {
        int id2 = id - W1R_ELEMS;
        int h    = id2 / 4608;
        int rem  = id2 - h * 4608;
        int tap  = rem >> 9;
        int rem2 = rem & 511;
        int n    = rem2 >> 5;
        int c    = rem2 & 31;
        float v = 0.f;
        if (n < 5)
            v = W2[(n * HIDD + h * 32 + c) * 9 + tap];  // W2 [5][64][3][3]
        W2r[id2] = (__bf16)v;
    }
}

// ---------------------------------------------------------------------------
// Fused phi (+ optional cost of its INPUT tile).  r11 kernel (475.1us);
// conv pipeline UNTOUCHED.  New in r12 (cost/epilogue sections only):
//  * INP=0 cost additionally packs yobs(bf16)+maskbits -> ym (one store).
//  * INP=1 cost reads its pixel from the staged sx tile (one ds_read_b128,
//    bit-identical to the global x_pk value) instead of a global load.
//  * OUTP=1 epilogue blend: ONE 16-B ym load per pixel replaces the gtm
//    maskbits load + ~2.5 scattered fp32 yobs loads.  Stored value is
//    bf16(yobs) either way -> numerically identical.
// LDS = 6400 + 25920 = 32320 -> 32768 -> 5 blocks/CU.
// ---------------------------------------------------------------------------
template<int INP, int OUTP>
__global__ __launch_bounds__(256, 4)
void phi_mfma(const float* __restrict__ xin,
              const __bf16* __restrict__ xin_pk,
              const __bf16* __restrict__ W1r, const __bf16* __restrict__ W2r,
              const float* __restrict__ b1, const float* __restrict__ b2,
              const float* __restrict__ gt, const float* __restrict__ yobs,
              const int* __restrict__ mask, unsigned* __restrict__ gtm,
              unsigned* __restrict__ ym,
              float* __restrict__ xout, __bf16* __restrict__ xout_pk,
              float* __restrict__ cpart, int blend)
{
    __shared__ __align__(16) char sx[400 * SX_PS];  // 6400 B (20x20 tile)
    __shared__ __align__(16) char sh[324 * SH_PS];  // 25920 B

    const int tid   = threadIdx.x;
    const int wv    = tid >> 6;
    const int lane  = tid & 63;
    const int l15   = lane & 15;
    const int quad  = lane >> 4;
    const int b     = blockIdx.z;
    const int gx0   = blockIdx.x * 16;
    const int gy0   = blockIdx.y * 16;

    // ---- stage x tile 20x20 (halo 2): one b128 write per pixel ----
    for (int p = tid; p < 400; p += 256) {
        const int u  = p / 20;
        const int v  = p - u * 20;
        const int gx = gx0 + u - 2;
        const int gy = gy0 + v - 2;
        bf16x8 pix = {(__bf16)0.f,(__bf16)0.f,(__bf16)0.f,(__bf16)0.f,
                      (__bf16)0.f,(__bf16)0.f,(__bf16)0.f,(__bf16)0.f};
        if (gx >= 0 && gx < NXD && gy >= 0 && gy < NYD) {
            if constexpr (INP == 0) {
                const float* src = xin + (size_t)b * VOL + (size_t)gx * NYD + gy;
                #pragma unroll
                for (int c = 0; c < TD; ++c) pix[c] = (__bf16)src[(size_t)c * PLANE];
            } else {
                pix = *(const bf16x8*)(xin_pk +
                        ((size_t)b * PLANE + (size_t)gx * NYD + gy) * 8);
            }
        }
        *(bf16x8*)(sx + p * SX_PS) = pix;
    }
    __syncthreads();

    // ---- fused cost of the INPUT x (rows 0..3) ----
    if (cpart) {
        const int ti = tid >> 4, tj = tid & 15;
        const int u  = ti + 2,  v  = tj + 2;
        const size_t pxi = (size_t)b * PLANE + (size_t)(gx0 + ti) * NYD + (gy0 + tj);
        const size_t gbase = (size_t)b * VOL + (size_t)(gx0 + ti) * NYD + (gy0 + tj);
        float mse = 0.f, dy = 0.f, q = 0.f;

        if constexpr (INP == 0) {
            // row 0: all-fp32 (exact); also pack gt/yobs/maskbits -> gtm, ym
            float gts[TD], yos[TD]; unsigned mb = 0;
            #pragma unroll
            for (int c = 0; c < TD; ++c) {
                const size_t gi = gbase + (size_t)c * PLANE;
                const float vv = xin[gi];
                const float g  = gt[gi];
                const float yo = yobs[gi];
                const int   m  = mask[gi];
                gts[c] = g; yos[c] = yo;
                if (m) mb |= 1u << c;
                mse += (g - vv) * (g - vv);
                float d = vv - yo;
                if (m) dy += d * d;
                float xp1 = (float)*(const __bf16*)(sx + (u * 20 + v + 1) * SX_PS + c * 2);
                float yp1 = (float)*(const __bf16*)(sx + ((u + 1) * 20 + v) * SX_PS + c * 2);
                float tp1 = (c < TD - 1)
                          ? (float)*(const __bf16*)(sx + (u * 20 + v) * SX_PS + (c + 1) * 2)
                          : 0.f;
                q += 6.01f * vv * vv - 2.f * vv * (xp1 + yp1 + tp1);
            }
            uint4 gv;
            gv.x = bpack(gts[0], gts[1]);
            gv.y = bpack(gts[2], gts[3]);
            gv.z = bpack(gts[4], 0.f);
            gv.w = mb;
            *(uint4*)(gtm + pxi * 4) = gv;
            uint4 yv;
            yv.x = bpack(yos[0], yos[1]);
            yv.y = bpack(yos[2], yos[3]);
            yv.z = bpack(yos[4], 0.f) | (mb << 16);
            yv.w = 0;
            *(uint4*)(ym + pxi * 4) = yv;
        } else {
            // rows 1..3: x from the staged sx tile (bit-identical to x_pk);
            // gt from gtm; dy == 0 exactly (blend made x_k = yobs at masked px).
            bf16x8 pxv = *(const bf16x8*)(sx + (u * 20 + v) * SX_PS);
            const uint4 gv = *(const uint4*)(gtm + pxi * 4);
            float gts[TD];
            gts[0] = bfu(gv.x & 0xffffu); gts[1] = bfu(gv.x >> 16);
            gts[2] = bfu(gv.y & 0xffffu); gts[3] = bfu(gv.y >> 16);
            gts[4] = bfu(gv.z & 0xffffu);
            #pragma unroll
            for (int c = 0; c < TD; ++c) {
                const float vv = (float)pxv[c];
                mse += (gts[c] - vv) * (gts[c] - vv);
                float xp1 = (float)*(const __bf16*)(sx + (u * 20 + v + 1) * SX_PS + c * 2);
                float yp1 = (float)*(const __bf16*)(sx + ((u + 1) * 20 + v) * SX_PS + c * 2);
                float tp1 = (c < TD - 1)
                          ? (float)*(const __bf16*)(sx + (u * 20 + v) * SX_PS + (c + 1) * 2)
                          : 0.f;
                q += 6.01f * vv * vv - 2.f * vv * (xp1 + yp1 + tp1);
            }
        }

        #pragma unroll
        for (int off = 32; off > 0; off >>= 1) {
            mse += __shfl_xor(mse, off, 64);
            dy  += __shfl_xor(dy,  off, 64);
            q   += __shfl_xor(q,   off, 64);
        }
        if (lane == 0) {
            float* pp = cpart + (((size_t)b * 1024 + blockIdx.y * 32 + blockIdx.x) * 4 + wv) * 3;
            pp[0] = mse; pp[1] = dy; pp[2] = q;
        }
    }

    f32x4 acc2[4] = {{0.f,0.f,0.f,0.f},{0.f,0.f,0.f,0.f},
                     {0.f,0.f,0.f,0.f},{0.f,0.f,0.f,0.f}};

    for (int half = 0; half < 2; ++half) {
        // ---- conv1 A (weight) frags + bias ----
        bf16x8 A1[2][3];
        f32x4  bias1[2];
        #pragma unroll
        for (int mt = 0; mt < 2; ++mt) {
            bias1[mt] = *(const f32x4*)(b1 + half * 32 + mt * 16 + quad * 4);
            #pragma unroll
            for (int kt = 0; kt < 3; ++kt)
                A1[mt][kt] = *(const bf16x8*)(W1r +
                    ((size_t)(kt * 64 + half * 32 + mt * 16 + l15) * 32 + quad * 8));
        }
        if (half) __syncthreads();   // prev conv2 reads of sh done

        // ---- conv1: 6 pixel n-tiles per wave ----
        #pragma unroll 2
        for (int nt = 0; nt < 6; ++nt) {
            const int ntg = wv * 6 + nt;
            const int p   = ntg * 16 + l15;   // pixel in padded 384 n-space
            const int pc  = (p < 324) ? p : 323;  // clamp pad lanes (write-guarded)
            const int i   = pc / 18;
            const int j   = pc - 18 * i;
            const int pb  = (i * 20 + j) * SX_PS;
            bf16x8 Bx[3];
            #pragma unroll
            for (int kt = 0; kt < 3; ++kt) {
                int tap = kt * 4 + quad;
                if (tap > 8) tap = 8;         // pad taps: weights zero, clamp addr
                Bx[kt] = *(const bf16x8*)(sx + pb + ((tap / 3) * 20 + tap % 3) * SX_PS);
            }
            #pragma unroll
            for (int mt = 0; mt < 2; ++mt) {
                f32x4 a = {0.f, 0.f, 0.f, 0.f};
                #pragma unroll
                for (int kt = 0; kt < 3; ++kt)
                    a = __builtin_amdgcn_mfma_f32_16x16x32_bf16(
                            A1[mt][kt], Bx[kt], a, 0, 0, 0);
                if (p < 324) {
                    bf16x4 hv;
                    #pragma unroll
                    for (int r = 0; r < 4; ++r)
                        hv[r] = (__bf16)fmaxf(a[r] + bias1[mt][r], 0.f);
                    *(bf16x4*)(sh + p * SH_PS + (mt * 16 + quad * 4) * 2) = hv;
                }
            }
        }
        __syncthreads();

        // ---- conv2: rolling 6-row x 3-shift window ----
        bf16x8 A2[9];
        #pragma unroll
        for (int tap = 0; tap < 9; ++tap)
            A2[tap] = *(const bf16x8*)(W2r +
                ((size_t)((half * 9 + tap) * 16 + l15) * 32 + quad * 8));

        const int shbase = (wv * 4 * 18 + l15) * SH_PS + quad * 16;
        bf16x8 R[6][3];
        #pragma unroll
        for (int rr = 0; rr < 3; ++rr)
            #pragma unroll
            for (int tx = 0; tx < 3; ++tx)
                R[rr][tx] = *(const bf16x8*)(sh + shbase + (rr * 18 + tx) * SH_PS);
        #pragma unroll
        for (int m = 0; m < 4; ++m) {
            #pragma unroll
            for (int dy2 = 0; dy2 < 3; ++dy2)
                #pragma unroll
                for (int tx = 0; tx < 3; ++tx)
                    acc2[m] = __builtin_amdgcn_mfma_f32_16x16x32_bf16(
                                  A2[dy2 * 3 + tx], R[m + dy2][tx], acc2[m], 0, 0, 0);
            if (m < 3) {
                #pragma unroll
                for (int tx = 0; tx < 3; ++tx)
                    R[m + 3][tx] = *(const bf16x8*)(sh + shbase +
                                                    ((m + 3) * 18 + tx) * SH_PS);
            }
        }
    }

    // ---- epilogue: D row = out-channel, col = pixel ----
    float b2v[4];
    #pragma unroll
    for (int r = 0; r < 4; ++r) {
        const int ch = quad * 4 + r;
        b2v[r] = (ch < TD) ? b2[ch] : 0.f;
    }
    if constexpr (OUTP == 0) {
        #pragma unroll
        for (int m = 0; m < 4; ++m) {
            const int ti2 = wv * 4 + m;
            const size_t rowoff = (size_t)b * VOL + (size_t)(gx0 + ti2) * NYD + (gy0 + l15);
            #pragma unroll
            for (int r = 0; r < 4; ++r) {
                const int ch = quad * 4 + r;
                if (ch < TD) {
                    const size_t off = rowoff + (size_t)ch * PLANE;
                    float o = acc2[m][r] + b2v[r];
                    if (blend && mask[off]) o = yobs[off];
                    xout[off] = o;
                }
            }
        }
    } else {
        const float b2_4 = b2[4];
        #pragma unroll
        for (int m = 0; m < 4; ++m) {
            const int ti2 = wv * 4 + m;
            // ch4 of row ti2, col l15 lives in quad-1 lane (16+l15), reg 0.
            const float c4 = __shfl(acc2[m][0], 16 + l15, 64) + b2_4;
            if (quad == 0) {
                const size_t pxo  = (size_t)b * PLANE +
                                    (size_t)(gx0 + ti2) * NYD + (gy0 + l15);
                float o[TD];
                #pragma unroll
                for (int r = 0; r < 4; ++r) o[r] = acc2[m][r] + b2v[r];
                o[4] = c4;
                if (blend) {
                    const uint4 yv = *(const uint4*)(ym + pxo * 4);
                    const unsigned mb = yv.z >> 16;
                    if (mb & 1u)  o[0] = bfu(yv.x & 0xffffu);
                    if (mb & 2u)  o[1] = bfu(yv.x >> 16);
                    if (mb & 4u)  o[2] = bfu(yv.y & 0xffffu);
                    if (mb & 8u)  o[3] = bfu(yv.y >> 16);
                    if (mb & 16u) o[4] = bfu(yv.z & 0xffffu);
                }
                bf16x8 pk = {(__bf16)o[0], (__bf16)o[1], (__bf16)o[2],
                             (__bf16)o[3], (__bf16)o[4],
                             (__bf16)0.f, (__bf16)0.f, (__bf16)0.f};
                *(bf16x8*)(xout_pk + pxo * 8) = pk;
            }
        }
    }
}

// ---------------------------------------------------------------------------
// Standalone cost (for x5 only), PIXEL-parallel + gtm for gt/maskbits.
// yobs loaded fp32 only at masked channels (dy row 4 is nonzero: x5 unblended).
// ---------------------------------------------------------------------------
__global__ __launch_bounds__(256)
void cost_kernel(const float* __restrict__ x, const unsigned* __restrict__ gtm,
                 const float* __restrict__ yobs,
                 float* __restrict__ partial)
{
    const int b    = blockIdx.y;
    const int lane = threadIdx.x & 63;
    const int wave = threadIdx.x >> 6;
    const int px   = blockIdx.x * 256 + threadIdx.x;   // 0..262143
    const int i    = px >> 9;           // row (x index)
    const int j    = px & 511;          // col (y index)
    const size_t pxi   = (size_t)b * PLANE + px;
    const size_t gbase = (size_t)b * VOL + px;

    float xv[TD];
    #pragma unroll
    for (int c = 0; c < TD; ++c) xv[c] = x[gbase + (size_t)c * PLANE];

    const uint4 gv = *(const uint4*)(gtm + pxi * 4);
    float gts[TD];
    gts[0] = bfu(gv.x & 0xffffu); gts[1] = bfu(gv.x >> 16);
    gts[2] = bfu(gv.y & 0xffffu); gts[3] = bfu(gv.y >> 16);
    gts[4] = bfu(gv.z & 0xffffu);
    const unsigned mb = gv.w;

    float mse = 0.f, dy = 0.f, q = 0.f;
    #pragma unroll
    for (int c = 0; c < TD; ++c) {
        const size_t gi = gbase + (size_t)c * PLANE;
        const float v  = xv[c];
        mse += (gts[c] - v) * (gts[c] - v);
        if ((mb >> c) & 1) {
            float d = v - yobs[gi];
            dy += d * d;
        }
        float tp1 = (c < TD - 1) ? xv[c + 1] : 0.f;            // t-neighbor
        float yp1 = __shfl_down(xv[c], 1, 64);                 // j-neighbor
        if (lane == 63) yp1 = (j < NYD - 1) ? x[gi + 1] : 0.f;
        float xp1 = (i < NXD - 1) ? x[gi + NYD] : 0.f;         // i-neighbor
        q += 6.01f * v * v - 2.f * v * (tp1 + yp1 + xp1);
    }

    #pragma unroll
    for (int off = 32; off > 0; off >>= 1) {
        mse += __shfl_xor(mse, off, 64);
        dy  += __shfl_xor(dy,  off, 64);
        q   += __shfl_xor(q,   off, 64);
    }
    if (lane == 0) {
        float* p = partial + (((size_t)b * CBLK + blockIdx.x) * 4 + wave) * 3;
        p[0] = mse; p[1] = dy; p[2] = q;
    }
}

// cpart layout: [row r=0..4][b=0..3][4096][3].  out cmp_loss [B=4][5][2].
__global__ __launch_bounds__(256)
void finalize_kernel(const float* __restrict__ cpart,
                     float* __restrict__ out)
{
    const int r = blockIdx.x / BD;
    const int b = blockIdx.x - r * BD;
    const float* base = cpart + ((size_t)r * BD + b) * 4096 * 3;
    float mse = 0.f, dy = 0.f, q = 0.f;
    for (int k = threadIdx.x; k < 4096; k += 256) {
        mse += base[k * 3 + 0];
        dy  += base[k * 3 + 1];
        q   += base[k * 3 + 2];
    }
    #pragma unroll
    for (int off = 32; off > 0; off >>= 1) {
        mse += __shfl_xor(mse, off, 64);
        dy  += __shfl_xor(dy,  off, 64);
        q   += __shfl_xor(q,   off, 64);
    }
    __shared__ float red[3][4];
    const int wave = threadIdx.x >> 6;
    const int lane = threadIdx.x & 63;
    if (lane == 0) { red[0][wave] = mse; red[1][wave] = dy; red[2][wave] = q; }
    __syncthreads();
    if (threadIdx.x == 0) {
        float m  = red[0][0] + red[0][1] + red[0][2] + red[0][3];
        float d  = red[1][0] + red[1][1] + red[1][2] + red[1][3];
        float qq = red[2][0] + red[2][1] + red[2][2] + red[2][3];
        out[b * 10 + r * 2 + 0] = m / (float)VOL;
        out[b * 10 + r * 2 + 1] = 1000.f * d + qq;
    }
}

extern "C" void kernel_launch(void* const* d_in, const int* in_sizes, int n_in,
                              void* d_out, int out_size, void* d_ws, size_t ws_size,
                              hipStream_t stream)
{
    const float* gt   = (const float*)d_in[0];
    const float* x0   = (const float*)d_in[1];
    const float* yobs = (const float*)d_in[2];
    const int*   mask = (const int*)d_in[3];
    const float* W1   = (const float*)d_in[4];
    const float* b1   = (const float*)d_in[5];
    const float* W2   = (const float*)d_in[6];
    const float* b2   = (const float*)d_in[7];

    float* out_x    = (float*)d_out;
    float* out_loss = out_x + (size_t)BD * VOL;

    float* wsA      = (float*)d_ws;                   // packed ping (16.8 MB)
    float* cpart    = wsA + (size_t)BD * VOL;         // 5*4*4096*3 floats
    __bf16* W1r     = (__bf16*)(cpart + 5 * BD * 4096 * 3);
    __bf16* W2r     = W1r + W1R_ELEMS;
    unsigned* gtm   = (unsigned*)(W2r + W2R_ELEMS);   // 16 B/px aux (16.8 MB)
    unsigned* ym    = gtm + (size_t)BD * PLANE * 4;   // 16 B/px aux (16.8 MB)
    const size_t PROW = (size_t)BD * 4096 * 3;        // per-row stride

    // Packed intermediate buffers: 4*262144*16 B = 16.8 MB each.
    // Pong aliases the out_x region (dead until iter 4 rewrites it fp32):
    //   x1 -> Pout, x2 -> Pws, x3 -> Pout, x4 -> Pws, x5 -> out_x (fp32).
    __bf16* Pout = (__bf16*)out_x;
    __bf16* Pws  = (__bf16*)wsA;

    dim3 pgrid(NXD / 16, NYD / 16, BD), pblock(256);
    dim3 cgrid(CBLK, BD), cblock(256);

    prep_weights<<<dim3(60), dim3(256), 0, stream>>>(W1, W2, W1r, W2r);

    phi_mfma<0,1><<<pgrid, pblock, 0, stream>>>(x0, nullptr, W1r, W2r, b1, b2,
        gt, yobs, mask, gtm, ym, nullptr, Pout, cpart + 0 * PROW, 1);
    phi_mfma<1,1><<<pgrid, pblock, 0, stream>>>(nullptr, Pout, W1r, W2r, b1, b2,
        gt, yobs, mask, gtm, ym, nullptr, Pws,  cpart + 1 * PROW, 1);
    phi_mfma<1,1><<<pgrid, pblock, 0, stream>>>(nullptr, Pws,  W1r, W2r, b1, b2,
        gt, yobs, mask, gtm, ym, nullptr, Pout, cpart + 2 * PROW, 1);
    phi_mfma<1,1><<<pgrid, pblock, 0, stream>>>(nullptr, Pout, W1r, W2r, b1, b2,
        gt, yobs, mask, gtm, ym, nullptr, Pws,  cpart + 3 * PROW, 1);
    // x5 = phi(x4), no blend, fp32 output (cost_kernel + harness consumer)
    phi_mfma<1,0><<<pgrid, pblock, 0, stream>>>(nullptr, Pws,  W1r, W2r, b1, b2,
        gt, yobs, mask, gtm, ym, out_x, nullptr, nullptr, 0);
    // cost(x5) -> row 4
    cost_kernel<<<cgrid, cblock, 0, stream>>>(out_x, gtm, yobs, cpart + 4 * PROW);

    finalize_kernel<<<dim3(5 * BD), dim3(256), 0, stream>>>(cpart, out_loss);
}